// Round 3
// baseline (1264.908 us; speedup 1.0000x reference)
//
#include <hip/hip_runtime.h>
#include <math.h>

#define NN 50000
#define NE 800000
#define IND 256
#define NH 64
#define DEPTH 4
#define NPW 8    // nodes per wave, fused_layer
#define GNPW 4   // nodes per wave, gate_update

// ---------------- CSR build ----------------

__global__ void count_deg(const int* __restrict__ src, const int* __restrict__ dst,
                          int* __restrict__ degin, int* __restrict__ degout) {
    int e = blockIdx.x * blockDim.x + threadIdx.x;
    if (e < NE) {
        atomicAdd(&degout[src[e]], 1);
        atomicAdd(&degin[dst[e]], 1);
    }
}

// block b scans input b: exclusive scan of n ints, out has n+1 entries
__global__ void scan2(const int* __restrict__ in0, int* __restrict__ out0,
                      const int* __restrict__ in1, int* __restrict__ out1, int n) {
    __shared__ int sums[1024];
    const int* in = blockIdx.x ? in1 : in0;
    int* out = blockIdx.x ? out1 : out0;
    int t = threadIdx.x;
    int chunk = (n + 1023) / 1024;
    int lo = t * chunk;
    int hi = lo + chunk; if (hi > n) hi = n;
    int s = 0;
    for (int i = lo; i < hi; ++i) s += in[i];
    sums[t] = s;
    __syncthreads();
    for (int off = 1; off < 1024; off <<= 1) {
        int v = (t >= off) ? sums[t - off] : 0;
        __syncthreads();
        sums[t] += v;
        __syncthreads();
    }
    int run = (t == 0) ? 0 : sums[t - 1];
    for (int i = lo; i < hi; ++i) { out[i] = run; run += in[i]; }
    if (t == 0) out[n] = sums[1023];
}

__global__ void init_node(const int* __restrict__ degin, const int* __restrict__ degout,
                          const int* __restrict__ off_dst, const int* __restrict__ off_src,
                          int* __restrict__ cur_dst, int* __restrict__ cur_src,
                          float* __restrict__ dis, float* __restrict__ cntf) {
    int i = blockIdx.x * blockDim.x + threadIdx.x;
    if (i < NN) {
        dis[i] = rsqrtf((float)(degin[i] + 1));   // +1 self loop; always >0
        int od = degout[i];
        cntf[i] = (float)(od > 0 ? od : 1);
        cur_dst[i] = off_dst[i];
        cur_src[i] = off_src[i];
    }
}

__global__ void fill_csr(const int* __restrict__ src, const int* __restrict__ dst,
                         int* __restrict__ cur_dst, int* __restrict__ cur_src,
                         int* __restrict__ srcs_by_dst, int* __restrict__ dsts_by_src) {
    int e = blockIdx.x * blockDim.x + threadIdx.x;
    if (e < NE) {
        int s = src[e], d = dst[e];
        int p = atomicAdd(&cur_dst[d], 1);
        srcs_by_dst[p] = s;
        int q = atomicAdd(&cur_src[s], 1);
        dsts_by_src[q] = d;
    }
}

// ---------------- helpers ----------------

__device__ __forceinline__ float4 bfly_sum(float4 v) {
    v.x += __shfl_xor(v.x, 16); v.y += __shfl_xor(v.y, 16);
    v.z += __shfl_xor(v.z, 16); v.w += __shfl_xor(v.w, 16);
    v.x += __shfl_xor(v.x, 32); v.y += __shfl_xor(v.y, 32);
    v.z += __shfl_xor(v.z, 32); v.w += __shfl_xor(v.w, 32);
    return v;
}

__device__ __forceinline__ float4 f4add(float4 a, float4 b) {
    return make_float4(a.x + b.x, a.y + b.y, a.z + b.z, a.w + b.w);
}

// ---------------- GEMM: [n,K] @ [K,64], 64 rows per block ----------------
// WSC: also write out2[row] = rowscale[row] * result (post-activation)
template<int K, bool RELU, bool WSC>
__global__ __launch_bounds__(256) void gemm64b(const float* __restrict__ X,
                                               const float* __restrict__ W,
                                               const float* __restrict__ bias,
                                               const float* __restrict__ rowscale,
                                               float* __restrict__ out,
                                               float* __restrict__ out2, int n) {
    __shared__ float Ws[64 * 64];
    __shared__ float Xs[64][68];
    int tid = threadIdx.x;
    int row0 = blockIdx.x * 64;
    int r16 = tid >> 4;      // 0..15
    int cg = tid & 15;       // 0..15
    float4 acc[4];
#pragma unroll
    for (int t = 0; t < 4; ++t) acc[t] = make_float4(0.f, 0.f, 0.f, 0.f);

    for (int kc = 0; kc < K; kc += 64) {
        const float4* W4 = (const float4*)(W + (size_t)kc * 64);
        float4* Ws4 = (float4*)Ws;
#pragma unroll
        for (int t = 0; t < 4; ++t) Ws4[tid + t * 256] = W4[tid + t * 256];
#pragma unroll
        for (int t = 0; t < 4; ++t) {
            int r = r16 + t * 16;
            int grow = row0 + r;
            float4 xv = make_float4(0.f, 0.f, 0.f, 0.f);
            if (grow < n) xv = *(const float4*)(X + (size_t)grow * K + kc + cg * 4);
            Xs[r][cg * 4 + 0] = xv.x; Xs[r][cg * 4 + 1] = xv.y;
            Xs[r][cg * 4 + 2] = xv.z; Xs[r][cg * 4 + 3] = xv.w;
        }
        __syncthreads();
#pragma unroll
        for (int k = 0; k < 64; ++k) {
            float4 w4 = ((const float4*)Ws)[k * 16 + cg];
#pragma unroll
            for (int t = 0; t < 4; ++t) {
                float xv = Xs[r16 + t * 16][k];
                acc[t].x += xv * w4.x; acc[t].y += xv * w4.y;
                acc[t].z += xv * w4.z; acc[t].w += xv * w4.w;
            }
        }
        __syncthreads();
    }

    float4 b4 = ((const float4*)bias)[cg];
#pragma unroll
    for (int t = 0; t < 4; ++t) {
        int row = row0 + r16 + t * 16;
        if (row < n) {
            float4 o;
            o.x = acc[t].x + b4.x; o.y = acc[t].y + b4.y;
            o.z = acc[t].z + b4.z; o.w = acc[t].w + b4.w;
            if (RELU) {
                o.x = fmaxf(o.x, 0.f); o.y = fmaxf(o.y, 0.f);
                o.z = fmaxf(o.z, 0.f); o.w = fmaxf(o.w, 0.f);
            }
            ((float4*)(out + (size_t)row * 64))[cg] = o;
            if (WSC) {
                float s = rowscale[row];
                float4 o2 = make_float4(o.x * s, o.y * s, o.z * s, o.w * s);
                ((float4*)(out2 + (size_t)row * 64))[cg] = o2;
            }
        }
    }
}

// ---------------- fused layer: Z-aggregation + dual GEMV ----------------
// Xsc[i] = dis_i * X[i] precomputed.
// Z[i] = dis_i * (sum_{s in in(i)} Xsc[s] + Xsc[i])
// B[i] = relu(Z[i] @ Wb + bb)   (conv candidate X_)
// C[i] = relu(Z[i] @ Wc + bc)   (gate xg)
// Persistent: grid-stride at wave granularity.
__global__ __launch_bounds__(256, 4) void fused_layer(
    const float* __restrict__ Xsc,
    const float* __restrict__ Wb, const float* __restrict__ bb,
    const float* __restrict__ Wc, const float* __restrict__ bc,
    const int* __restrict__ off, const int* __restrict__ nbr,
    const float* __restrict__ dis,
    float* __restrict__ B, float* __restrict__ C, int gwaves)
{
    __shared__ float Ws[2][64 * 64];
    int tid = threadIdx.x;
    {
        const float4* wb4 = (const float4*)Wb;
        const float4* wc4 = (const float4*)Wc;
        float4* s0 = (float4*)Ws[0];
        float4* s1 = (float4*)Ws[1];
#pragma unroll
        for (int t = 0; t < 4; ++t) {
            s0[tid + t * 256] = wb4[tid + t * 256];
            s1[tid + t * 256] = wc4[tid + t * 256];
        }
    }
    __syncthreads();

    int lane = tid & 63;
    int q = lane >> 4;       // quarter 0..3
    int c = lane & 15;       // float4 group 0..15
    float4 bbv = ((const float4*)bb)[c];
    float4 bcv = ((const float4*)bc)[c];

    int wave = blockIdx.x * 4 + (tid >> 6);

    for (int node0 = wave * NPW; node0 < NN; node0 += gwaves * NPW) {
        int nodeEnd = node0 + NPW; if (nodeEnd > NN) nodeEnd = NN;
        for (int node = node0; node < nodeEnd; ++node) {
            int lo = off[node], hi = off[node + 1];
            float4 self = *(const float4*)(Xsc + (size_t)node * 64 + c * 4);
            float di = dis[node];

            float4 z = make_float4(0.f, 0.f, 0.f, 0.f);
            int j = lo + q;
            // unrolled x4: 4 independent row loads in flight per quarter
            for (; j + 12 < hi; j += 16) {
                int s0 = nbr[j], s1 = nbr[j + 4], s2 = nbr[j + 8], s3 = nbr[j + 12];
                float4 r0 = *(const float4*)(Xsc + (size_t)s0 * 64 + c * 4);
                float4 r1 = *(const float4*)(Xsc + (size_t)s1 * 64 + c * 4);
                float4 r2 = *(const float4*)(Xsc + (size_t)s2 * 64 + c * 4);
                float4 r3 = *(const float4*)(Xsc + (size_t)s3 * 64 + c * 4);
                z = f4add(z, f4add(f4add(r0, r1), f4add(r2, r3)));
            }
            for (; j < hi; j += 4) {
                int s = nbr[j];
                z = f4add(z, *(const float4*)(Xsc + (size_t)s * 64 + c * 4));
            }
            z = bfly_sum(z);
            z.x = di * (z.x + self.x);
            z.y = di * (z.y + self.y);
            z.z = di * (z.z + self.z);
            z.w = di * (z.w + self.w);

            // dual GEMV: lane (q,c) covers k in [16q,16q+16), outputs 4c..4c+3
            float4 ab = make_float4(0.f, 0.f, 0.f, 0.f);
            float4 ac = make_float4(0.f, 0.f, 0.f, 0.f);
#pragma unroll
            for (int kk = 0; kk < 16; ++kk) {
                float zsrc = ((kk & 3) == 0) ? z.x : ((kk & 3) == 1) ? z.y
                           : ((kk & 3) == 2) ? z.z : z.w;
                float zk = __shfl(zsrc, q * 4 + (kk >> 2));
                int k = q * 16 + kk;
                float4 wb = *(const float4*)&Ws[0][k * 64 + c * 4];
                float4 wc = *(const float4*)&Ws[1][k * 64 + c * 4];
                ab.x += zk * wb.x; ab.y += zk * wb.y; ab.z += zk * wb.z; ab.w += zk * wb.w;
                ac.x += zk * wc.x; ac.y += zk * wc.y; ac.z += zk * wc.z; ac.w += zk * wc.w;
            }
            ab = bfly_sum(ab);
            ac = bfly_sum(ac);
            if (q == 0) {
                float4 o;
                o.x = fmaxf(ab.x + bbv.x, 0.f); o.y = fmaxf(ab.y + bbv.y, 0.f);
                o.z = fmaxf(ab.z + bbv.z, 0.f); o.w = fmaxf(ab.w + bbv.w, 0.f);
                *(float4*)(B + (size_t)node * 64 + c * 4) = o;
            } else if (q == 1) {
                float4 o;
                o.x = fmaxf(ac.x + bcv.x, 0.f); o.y = fmaxf(ac.y + bcv.y, 0.f);
                o.z = fmaxf(ac.z + bcv.z, 0.f); o.w = fmaxf(ac.w + bcv.w, 0.f);
                *(float4*)(C + (size_t)node * 64 + c * 4) = o;
            }
        }
    }
}

// ---------------- gate + convex update ----------------
// tau = tanh( sum_{d in out(i)} (xg_i - xg_d)^2 / cnt_i )   per channel
// X = (1-tau)*X + tau*Xn ; Xsc = dis*X (for next layer's gather)
__global__ __launch_bounds__(256, 8) void gate_update4(
    const float* __restrict__ XG, const float* __restrict__ Xn,
    float* __restrict__ X, float* __restrict__ Xsc,
    const int* __restrict__ off, const int* __restrict__ nbr,
    const float* __restrict__ cntf, const float* __restrict__ dis)
{
    int tid = threadIdx.x;
    int lane = tid & 63;
    int q = lane >> 4;
    int c = lane & 15;
    int wave = blockIdx.x * 4 + (tid >> 6);
    int node0 = wave * GNPW;
    int nodeEnd = node0 + GNPW; if (nodeEnd > NN) nodeEnd = NN;

    for (int node = node0; node < nodeEnd; ++node) {
        float4 xg = *(const float4*)(XG + (size_t)node * 64 + c * 4);
        float4 xo = *(const float4*)(X + (size_t)node * 64 + c * 4);
        float4 xn = *(const float4*)(Xn + (size_t)node * 64 + c * 4);
        float inv = 1.f / cntf[node];
        float di = dis[node];

        float4 acc = make_float4(0.f, 0.f, 0.f, 0.f);
        int lo = off[node], hi = off[node + 1];
        int j = lo + q;
        for (; j + 12 < hi; j += 16) {
            int d0 = nbr[j], d1 = nbr[j + 4], d2 = nbr[j + 8], d3 = nbr[j + 12];
            float4 r0 = *(const float4*)(XG + (size_t)d0 * 64 + c * 4);
            float4 r1 = *(const float4*)(XG + (size_t)d1 * 64 + c * 4);
            float4 r2 = *(const float4*)(XG + (size_t)d2 * 64 + c * 4);
            float4 r3 = *(const float4*)(XG + (size_t)d3 * 64 + c * 4);
            float e;
            e = xg.x - r0.x; acc.x += e * e;  e = xg.y - r0.y; acc.y += e * e;
            e = xg.z - r0.z; acc.z += e * e;  e = xg.w - r0.w; acc.w += e * e;
            e = xg.x - r1.x; acc.x += e * e;  e = xg.y - r1.y; acc.y += e * e;
            e = xg.z - r1.z; acc.z += e * e;  e = xg.w - r1.w; acc.w += e * e;
            e = xg.x - r2.x; acc.x += e * e;  e = xg.y - r2.y; acc.y += e * e;
            e = xg.z - r2.z; acc.z += e * e;  e = xg.w - r2.w; acc.w += e * e;
            e = xg.x - r3.x; acc.x += e * e;  e = xg.y - r3.y; acc.y += e * e;
            e = xg.z - r3.z; acc.z += e * e;  e = xg.w - r3.w; acc.w += e * e;
        }
        for (; j < hi; j += 4) {
            int d = nbr[j];
            float4 xd = *(const float4*)(XG + (size_t)d * 64 + c * 4);
            float e;
            e = xg.x - xd.x; acc.x += e * e;  e = xg.y - xd.y; acc.y += e * e;
            e = xg.z - xd.z; acc.z += e * e;  e = xg.w - xd.w; acc.w += e * e;
        }
        acc = bfly_sum(acc);
        if (q == 0) {
            float4 tau;
            tau.x = tanhf(acc.x * inv); tau.y = tanhf(acc.y * inv);
            tau.z = tanhf(acc.z * inv); tau.w = tanhf(acc.w * inv);
            float4 o;
            o.x = xo.x + tau.x * (xn.x - xo.x);
            o.y = xo.y + tau.y * (xn.y - xo.y);
            o.z = xo.z + tau.z * (xn.z - xo.z);
            o.w = xo.w + tau.w * (xn.w - xo.w);
            *(float4*)(X + (size_t)node * 64 + c * 4) = o;
            float4 o2 = make_float4(o.x * di, o.y * di, o.z * di, o.w * di);
            *(float4*)(Xsc + (size_t)node * 64 + c * 4) = o2;
        }
    }
}

// ---------------- launch ----------------

extern "C" void kernel_launch(void* const* d_in, const int* in_sizes, int n_in,
                              void* d_out, int out_size, void* d_ws, size_t ws_size,
                              hipStream_t stream) {
    const float* x      = (const float*)d_in[0];
    const int*   ei     = (const int*)d_in[1];
    const float* enc_w  = (const float*)d_in[2];
    const float* enc_b  = (const float*)d_in[3];
    const float* conv_w = (const float*)d_in[4];
    const float* conv_b = (const float*)d_in[5];
    const float* gg_w   = (const float*)d_in[6];
    const float* gg_b   = (const float*)d_in[7];
    const float* dec_w  = (const float*)d_in[8];
    const float* dec_b  = (const float*)d_in[9];
    float* out = (float*)d_out;

    const int* src = ei;
    const int* dst = ei + NE;

    char* p = (char*)d_ws;
    auto alloc = [&](size_t bytes) -> void* {
        void* r = (void*)p;
        p += (bytes + 255) & ~(size_t)255;
        return r;
    };
    float* X    = (float*)alloc((size_t)NN * 64 * 4);
    float* Xsc  = (float*)alloc((size_t)NN * 64 * 4);
    float* B    = (float*)alloc((size_t)NN * 64 * 4);   // X_ candidate
    float* C    = (float*)alloc((size_t)NN * 64 * 4);   // xg
    float* dis  = (float*)alloc((size_t)NN * 4);
    float* cntf = (float*)alloc((size_t)NN * 4);
    int* degin   = (int*)alloc((size_t)NN * 4);
    int* degout  = (int*)alloc((size_t)NN * 4);
    int* off_dst = (int*)alloc((size_t)(NN + 1) * 4);
    int* off_src = (int*)alloc((size_t)(NN + 1) * 4);
    int* cur_dst = (int*)alloc((size_t)NN * 4);
    int* cur_src = (int*)alloc((size_t)NN * 4);
    int* sbd     = (int*)alloc((size_t)NE * 4);   // srcs grouped by dst
    int* dbs     = (int*)alloc((size_t)NE * 4);   // dsts grouped by src

    hipMemsetAsync(degin, 0, (size_t)NN * 4, stream);
    hipMemsetAsync(degout, 0, (size_t)NN * 4, stream);

    const int EB = (NE + 255) / 256;
    const int NB = (NN + 255) / 256;
    count_deg<<<EB, 256, 0, stream>>>(src, dst, degin, degout);
    scan2<<<2, 1024, 0, stream>>>(degin, off_dst, degout, off_src, NN);
    init_node<<<NB, 256, 0, stream>>>(degin, degout, off_dst, off_src,
                                      cur_dst, cur_src, dis, cntf);
    fill_csr<<<EB, 256, 0, stream>>>(src, dst, cur_dst, cur_src, sbd, dbs);

    const int GB = (NN + 63) / 64;                        // gemm blocks (64 rows)
    const int FLB = 1024;                                 // persistent fused blocks
    const int FLW = FLB * 4;                              // waves in fused grid
    const int GUB = ((NN + GNPW - 1) / GNPW + 3) / 4;     // gate blocks

    // encoder: X = relu(x@enc_w+b); Xsc = dis*X
    gemm64b<IND, true, true><<<GB, 256, 0, stream>>>(x, enc_w, enc_b, dis, X, Xsc, NN);

    for (int l = 0; l < DEPTH; ++l) {
        fused_layer<<<FLB, 256, 0, stream>>>(Xsc, conv_w, conv_b, gg_w, gg_b,
                                             off_dst, sbd, dis, B, C, FLW);
        gate_update4<<<GUB, 256, 0, stream>>>(C, B, X, Xsc, off_src, dbs, cntf, dis);
    }

    // decoder
    gemm64b<NH, true, false><<<GB, 256, 0, stream>>>(X, dec_w, dec_b, nullptr, out, nullptr, NN);
}

// Round 4
// 935.226 us; speedup vs baseline: 1.3525x; 1.3525x over previous
//
#include <hip/hip_runtime.h>
#include <math.h>

#define NN 50000
#define NE 800000
#define IND 256
#define NH 64
#define DEPTH 4
#define NPW 8    // nodes per wave, fused_layer
#define GNPW 4   // nodes per wave, gate_update

// ---------------- bf16 helpers ----------------

__device__ __forceinline__ float bf2f(unsigned short u) {
    return __uint_as_float(((unsigned int)u) << 16);
}
__device__ __forceinline__ unsigned short f2bf(float f) {
    unsigned int x = __float_as_uint(f);
    unsigned int r = (x + 0x7fffu + ((x >> 16) & 1u)) >> 16;
    return (unsigned short)r;
}
__device__ __forceinline__ float4 us4_to_f4(ushort4 u) {
    return make_float4(bf2f(u.x), bf2f(u.y), bf2f(u.z), bf2f(u.w));
}
__device__ __forceinline__ ushort4 f4_to_us4(float4 f) {
    ushort4 u;
    u.x = f2bf(f.x); u.y = f2bf(f.y); u.z = f2bf(f.z); u.w = f2bf(f.w);
    return u;
}

// ---------------- CSR build ----------------

__global__ void count_deg(const int* __restrict__ src, const int* __restrict__ dst,
                          int* __restrict__ degin, int* __restrict__ degout) {
    int e = blockIdx.x * blockDim.x + threadIdx.x;
    if (e < NE) {
        atomicAdd(&degout[src[e]], 1);
        atomicAdd(&degin[dst[e]], 1);
    }
}

// block b scans input b: exclusive scan of n ints, out has n+1 entries
__global__ void scan2(const int* __restrict__ in0, int* __restrict__ out0,
                      const int* __restrict__ in1, int* __restrict__ out1, int n) {
    __shared__ int sums[1024];
    const int* in = blockIdx.x ? in1 : in0;
    int* out = blockIdx.x ? out1 : out0;
    int t = threadIdx.x;
    int chunk = (n + 1023) / 1024;
    int lo = t * chunk;
    int hi = lo + chunk; if (hi > n) hi = n;
    int s = 0;
    for (int i = lo; i < hi; ++i) s += in[i];
    sums[t] = s;
    __syncthreads();
    for (int off = 1; off < 1024; off <<= 1) {
        int v = (t >= off) ? sums[t - off] : 0;
        __syncthreads();
        sums[t] += v;
        __syncthreads();
    }
    int run = (t == 0) ? 0 : sums[t - 1];
    for (int i = lo; i < hi; ++i) { out[i] = run; run += in[i]; }
    if (t == 0) out[n] = sums[1023];
}

__global__ void init_node(const int* __restrict__ degin, const int* __restrict__ degout,
                          const int* __restrict__ off_dst, const int* __restrict__ off_src,
                          int* __restrict__ cur_dst, int* __restrict__ cur_src,
                          float* __restrict__ dis, float* __restrict__ cntf) {
    int i = blockIdx.x * blockDim.x + threadIdx.x;
    if (i < NN) {
        dis[i] = rsqrtf((float)(degin[i] + 1));   // +1 self loop; always >0
        int od = degout[i];
        cntf[i] = (float)(od > 0 ? od : 1);
        cur_dst[i] = off_dst[i];
        cur_src[i] = off_src[i];
    }
}

__global__ void fill_csr(const int* __restrict__ src, const int* __restrict__ dst,
                         int* __restrict__ cur_dst, int* __restrict__ cur_src,
                         int* __restrict__ srcs_by_dst, int* __restrict__ dsts_by_src) {
    int e = blockIdx.x * blockDim.x + threadIdx.x;
    if (e < NE) {
        int s = src[e], d = dst[e];
        int p = atomicAdd(&cur_dst[d], 1);
        srcs_by_dst[p] = s;
        int q = atomicAdd(&cur_src[s], 1);
        dsts_by_src[q] = d;
    }
}

// ---------------- helpers ----------------

__device__ __forceinline__ float4 bfly_sum(float4 v) {
    v.x += __shfl_xor(v.x, 16); v.y += __shfl_xor(v.y, 16);
    v.z += __shfl_xor(v.z, 16); v.w += __shfl_xor(v.w, 16);
    v.x += __shfl_xor(v.x, 32); v.y += __shfl_xor(v.y, 32);
    v.z += __shfl_xor(v.z, 32); v.w += __shfl_xor(v.w, 32);
    return v;
}

// ---------------- GEMM: [n,K] @ [K,64], 64 rows per block ----------------
// WSC: also write xsc row = bf16(rowscale[row] * result)
template<int K, bool RELU, bool WSC>
__global__ __launch_bounds__(256) void gemm64b(const float* __restrict__ X,
                                               const float* __restrict__ W,
                                               const float* __restrict__ bias,
                                               const float* __restrict__ rowscale,
                                               float* __restrict__ out,
                                               unsigned short* __restrict__ xsc, int n) {
    __shared__ float Ws[64 * 64];
    __shared__ float Xs[64][68];
    int tid = threadIdx.x;
    int row0 = blockIdx.x * 64;
    int r16 = tid >> 4;      // 0..15
    int cg = tid & 15;       // 0..15
    float4 acc[4];
#pragma unroll
    for (int t = 0; t < 4; ++t) acc[t] = make_float4(0.f, 0.f, 0.f, 0.f);

    for (int kc = 0; kc < K; kc += 64) {
        const float4* W4 = (const float4*)(W + (size_t)kc * 64);
        float4* Ws4 = (float4*)Ws;
#pragma unroll
        for (int t = 0; t < 4; ++t) Ws4[tid + t * 256] = W4[tid + t * 256];
#pragma unroll
        for (int t = 0; t < 4; ++t) {
            int r = r16 + t * 16;
            int grow = row0 + r;
            float4 xv = make_float4(0.f, 0.f, 0.f, 0.f);
            if (grow < n) xv = *(const float4*)(X + (size_t)grow * K + kc + cg * 4);
            Xs[r][cg * 4 + 0] = xv.x; Xs[r][cg * 4 + 1] = xv.y;
            Xs[r][cg * 4 + 2] = xv.z; Xs[r][cg * 4 + 3] = xv.w;
        }
        __syncthreads();
#pragma unroll
        for (int k = 0; k < 64; ++k) {
            float4 w4 = ((const float4*)Ws)[k * 16 + cg];
#pragma unroll
            for (int t = 0; t < 4; ++t) {
                float xv = Xs[r16 + t * 16][k];
                acc[t].x += xv * w4.x; acc[t].y += xv * w4.y;
                acc[t].z += xv * w4.z; acc[t].w += xv * w4.w;
            }
        }
        __syncthreads();
    }

    float4 b4 = ((const float4*)bias)[cg];
#pragma unroll
    for (int t = 0; t < 4; ++t) {
        int row = row0 + r16 + t * 16;
        if (row < n) {
            float4 o;
            o.x = acc[t].x + b4.x; o.y = acc[t].y + b4.y;
            o.z = acc[t].z + b4.z; o.w = acc[t].w + b4.w;
            if (RELU) {
                o.x = fmaxf(o.x, 0.f); o.y = fmaxf(o.y, 0.f);
                o.z = fmaxf(o.z, 0.f); o.w = fmaxf(o.w, 0.f);
            }
            ((float4*)(out + (size_t)row * 64))[cg] = o;
            if (WSC) {
                float s = rowscale[row];
                float4 o2 = make_float4(o.x * s, o.y * s, o.z * s, o.w * s);
                ((ushort4*)(xsc + (size_t)row * 64))[cg] = f4_to_us4(o2);
            }
        }
    }
}

// ---------------- fused layer: Z-aggregation + dual GEMV ----------------
// Xb (bf16) holds dis_i * X[i].
// Z[i] = dis_i * (sum_{s in in(i)} Xb[s] + Xb[i])
// B[i] = relu(Z[i] @ Wb + bb)   (conv candidate X_, fp32)
// C[i] = relu(Z[i] @ Wc + bc)   (gate xg, bf16)
__global__ __launch_bounds__(256) void fused_layer(
    const unsigned short* __restrict__ Xbf,
    const float* __restrict__ Wb, const float* __restrict__ bb,
    const float* __restrict__ Wc, const float* __restrict__ bc,
    const int* __restrict__ off, const int* __restrict__ nbr,
    const float* __restrict__ dis,
    float* __restrict__ B, unsigned short* __restrict__ Cbf)
{
    __shared__ float Ws[2][64 * 64];
    int tid = threadIdx.x;
    {
        const float4* wb4 = (const float4*)Wb;
        const float4* wc4 = (const float4*)Wc;
        float4* s0 = (float4*)Ws[0];
        float4* s1 = (float4*)Ws[1];
#pragma unroll
        for (int t = 0; t < 4; ++t) {
            s0[tid + t * 256] = wb4[tid + t * 256];
            s1[tid + t * 256] = wc4[tid + t * 256];
        }
    }
    __syncthreads();

    int lane = tid & 63;
    int q = lane >> 4;       // quarter 0..3
    int c = lane & 15;       // float4 / ushort4 group 0..15
    float4 bbv = ((const float4*)bb)[c];
    float4 bcv = ((const float4*)bc)[c];

    const ushort4* Xb = (const ushort4*)Xbf;   // row pitch = 16 ushort4

    int wave = blockIdx.x * 4 + (tid >> 6);
    int node0 = wave * NPW;
    int nodeEnd = node0 + NPW; if (nodeEnd > NN) nodeEnd = NN;

    for (int node = node0; node < nodeEnd; ++node) {
        int lo = off[node], hi = off[node + 1];
        float4 self = us4_to_f4(Xb[(size_t)node * 16 + c]);
        float di = dis[node];

        float4 z = make_float4(0.f, 0.f, 0.f, 0.f);
        int j = lo + q;
        // unrolled x4: 4 independent row loads in flight per quarter (16/wave)
        for (; j + 12 < hi; j += 16) {
            int s0 = nbr[j], s1 = nbr[j + 4], s2 = nbr[j + 8], s3 = nbr[j + 12];
            ushort4 r0 = Xb[(size_t)s0 * 16 + c];
            ushort4 r1 = Xb[(size_t)s1 * 16 + c];
            ushort4 r2 = Xb[(size_t)s2 * 16 + c];
            ushort4 r3 = Xb[(size_t)s3 * 16 + c];
            z.x += (bf2f(r0.x) + bf2f(r1.x)) + (bf2f(r2.x) + bf2f(r3.x));
            z.y += (bf2f(r0.y) + bf2f(r1.y)) + (bf2f(r2.y) + bf2f(r3.y));
            z.z += (bf2f(r0.z) + bf2f(r1.z)) + (bf2f(r2.z) + bf2f(r3.z));
            z.w += (bf2f(r0.w) + bf2f(r1.w)) + (bf2f(r2.w) + bf2f(r3.w));
        }
        for (; j < hi; j += 4) {
            int s = nbr[j];
            float4 r = us4_to_f4(Xb[(size_t)s * 16 + c]);
            z.x += r.x; z.y += r.y; z.z += r.z; z.w += r.w;
        }
        z = bfly_sum(z);
        z.x = di * (z.x + self.x);
        z.y = di * (z.y + self.y);
        z.z = di * (z.z + self.z);
        z.w = di * (z.w + self.w);

        // dual GEMV: lane (q,c) covers k in [16q,16q+16), outputs 4c..4c+3
        float4 ab = make_float4(0.f, 0.f, 0.f, 0.f);
        float4 ac = make_float4(0.f, 0.f, 0.f, 0.f);
#pragma unroll
        for (int kk = 0; kk < 16; ++kk) {
            float zsrc = ((kk & 3) == 0) ? z.x : ((kk & 3) == 1) ? z.y
                       : ((kk & 3) == 2) ? z.z : z.w;
            float zk = __shfl(zsrc, q * 4 + (kk >> 2));
            int k = q * 16 + kk;
            float4 wb = *(const float4*)&Ws[0][k * 64 + c * 4];
            float4 wc = *(const float4*)&Ws[1][k * 64 + c * 4];
            ab.x += zk * wb.x; ab.y += zk * wb.y; ab.z += zk * wb.z; ab.w += zk * wb.w;
            ac.x += zk * wc.x; ac.y += zk * wc.y; ac.z += zk * wc.z; ac.w += zk * wc.w;
        }
        ab = bfly_sum(ab);
        ac = bfly_sum(ac);
        if (q == 0) {
            float4 o;
            o.x = fmaxf(ab.x + bbv.x, 0.f); o.y = fmaxf(ab.y + bbv.y, 0.f);
            o.z = fmaxf(ab.z + bbv.z, 0.f); o.w = fmaxf(ab.w + bbv.w, 0.f);
            *(float4*)(B + (size_t)node * 64 + c * 4) = o;
        } else if (q == 1) {
            float4 o;
            o.x = fmaxf(ac.x + bcv.x, 0.f); o.y = fmaxf(ac.y + bcv.y, 0.f);
            o.z = fmaxf(ac.z + bcv.z, 0.f); o.w = fmaxf(ac.w + bcv.w, 0.f);
            ((ushort4*)Cbf)[(size_t)node * 16 + c] = f4_to_us4(o);
        }
    }
}

// ---------------- gate + convex update ----------------
// tau = tanh( sum_{d in out(i)} (xg_i - xg_d)^2 / cnt_i )   per channel
// X = (1-tau)*X + tau*Xn ; Xsc(bf16) = dis*X for next layer's gather
__global__ __launch_bounds__(256) void gate_update4(
    const unsigned short* __restrict__ Cbf, const float* __restrict__ Xn,
    float* __restrict__ X, unsigned short* __restrict__ Xbf,
    const int* __restrict__ off, const int* __restrict__ nbr,
    const float* __restrict__ cntf, const float* __restrict__ dis)
{
    int tid = threadIdx.x;
    int lane = tid & 63;
    int q = lane >> 4;
    int c = lane & 15;
    const ushort4* Cb = (const ushort4*)Cbf;
    int wave = blockIdx.x * 4 + (tid >> 6);
    int node0 = wave * GNPW;
    int nodeEnd = node0 + GNPW; if (nodeEnd > NN) nodeEnd = NN;

    for (int node = node0; node < nodeEnd; ++node) {
        float4 xg = us4_to_f4(Cb[(size_t)node * 16 + c]);
        float4 xo = *(const float4*)(X + (size_t)node * 64 + c * 4);
        float4 xn = *(const float4*)(Xn + (size_t)node * 64 + c * 4);
        float inv = 1.f / cntf[node];
        float di = dis[node];

        float4 acc = make_float4(0.f, 0.f, 0.f, 0.f);
        int lo = off[node], hi = off[node + 1];
        int j = lo + q;
        for (; j + 12 < hi; j += 16) {
            int d0 = nbr[j], d1 = nbr[j + 4], d2 = nbr[j + 8], d3 = nbr[j + 12];
            float4 r0 = us4_to_f4(Cb[(size_t)d0 * 16 + c]);
            float4 r1 = us4_to_f4(Cb[(size_t)d1 * 16 + c]);
            float4 r2 = us4_to_f4(Cb[(size_t)d2 * 16 + c]);
            float4 r3 = us4_to_f4(Cb[(size_t)d3 * 16 + c]);
            float e;
            e = xg.x - r0.x; acc.x += e * e;  e = xg.y - r0.y; acc.y += e * e;
            e = xg.z - r0.z; acc.z += e * e;  e = xg.w - r0.w; acc.w += e * e;
            e = xg.x - r1.x; acc.x += e * e;  e = xg.y - r1.y; acc.y += e * e;
            e = xg.z - r1.z; acc.z += e * e;  e = xg.w - r1.w; acc.w += e * e;
            e = xg.x - r2.x; acc.x += e * e;  e = xg.y - r2.y; acc.y += e * e;
            e = xg.z - r2.z; acc.z += e * e;  e = xg.w - r2.w; acc.w += e * e;
            e = xg.x - r3.x; acc.x += e * e;  e = xg.y - r3.y; acc.y += e * e;
            e = xg.z - r3.z; acc.z += e * e;  e = xg.w - r3.w; acc.w += e * e;
        }
        for (; j < hi; j += 4) {
            int d = nbr[j];
            float4 xd = us4_to_f4(Cb[(size_t)d * 16 + c]);
            float e;
            e = xg.x - xd.x; acc.x += e * e;  e = xg.y - xd.y; acc.y += e * e;
            e = xg.z - xd.z; acc.z += e * e;  e = xg.w - xd.w; acc.w += e * e;
        }
        acc = bfly_sum(acc);
        if (q == 0) {
            float4 tau;
            tau.x = tanhf(acc.x * inv); tau.y = tanhf(acc.y * inv);
            tau.z = tanhf(acc.z * inv); tau.w = tanhf(acc.w * inv);
            float4 o;
            o.x = xo.x + tau.x * (xn.x - xo.x);
            o.y = xo.y + tau.y * (xn.y - xo.y);
            o.z = xo.z + tau.z * (xn.z - xo.z);
            o.w = xo.w + tau.w * (xn.w - xo.w);
            *(float4*)(X + (size_t)node * 64 + c * 4) = o;
            float4 o2 = make_float4(o.x * di, o.y * di, o.z * di, o.w * di);
            ((ushort4*)Xbf)[(size_t)node * 16 + c] = f4_to_us4(o2);
        }
    }
}

// ---------------- launch ----------------

extern "C" void kernel_launch(void* const* d_in, const int* in_sizes, int n_in,
                              void* d_out, int out_size, void* d_ws, size_t ws_size,
                              hipStream_t stream) {
    const float* x      = (const float*)d_in[0];
    const int*   ei     = (const int*)d_in[1];
    const float* enc_w  = (const float*)d_in[2];
    const float* enc_b  = (const float*)d_in[3];
    const float* conv_w = (const float*)d_in[4];
    const float* conv_b = (const float*)d_in[5];
    const float* gg_w   = (const float*)d_in[6];
    const float* gg_b   = (const float*)d_in[7];
    const float* dec_w  = (const float*)d_in[8];
    const float* dec_b  = (const float*)d_in[9];
    float* out = (float*)d_out;

    const int* src = ei;
    const int* dst = ei + NE;

    char* p = (char*)d_ws;
    auto alloc = [&](size_t bytes) -> void* {
        void* r = (void*)p;
        p += (bytes + 255) & ~(size_t)255;
        return r;
    };
    float* X   = (float*)alloc((size_t)NN * 64 * 4);
    float* B   = (float*)alloc((size_t)NN * 64 * 4);           // X_ candidate (fp32)
    unsigned short* Xbf = (unsigned short*)alloc((size_t)NN * 64 * 2);  // dis*X, bf16
    unsigned short* Cbf = (unsigned short*)alloc((size_t)NN * 64 * 2);  // xg, bf16
    float* dis  = (float*)alloc((size_t)NN * 4);
    float* cntf = (float*)alloc((size_t)NN * 4);
    int* degin   = (int*)alloc((size_t)NN * 4);
    int* degout  = (int*)alloc((size_t)NN * 4);
    int* off_dst = (int*)alloc((size_t)(NN + 1) * 4);
    int* off_src = (int*)alloc((size_t)(NN + 1) * 4);
    int* cur_dst = (int*)alloc((size_t)NN * 4);
    int* cur_src = (int*)alloc((size_t)NN * 4);
    int* sbd     = (int*)alloc((size_t)NE * 4);   // srcs grouped by dst
    int* dbs     = (int*)alloc((size_t)NE * 4);   // dsts grouped by src

    hipMemsetAsync(degin, 0, (size_t)NN * 4, stream);
    hipMemsetAsync(degout, 0, (size_t)NN * 4, stream);

    const int EB = (NE + 255) / 256;
    const int NB = (NN + 255) / 256;
    count_deg<<<EB, 256, 0, stream>>>(src, dst, degin, degout);
    scan2<<<2, 1024, 0, stream>>>(degin, off_dst, degout, off_src, NN);
    init_node<<<NB, 256, 0, stream>>>(degin, degout, off_dst, off_src,
                                      cur_dst, cur_src, dis, cntf);
    fill_csr<<<EB, 256, 0, stream>>>(src, dst, cur_dst, cur_src, sbd, dbs);

    const int GB  = (NN + 63) / 64;                       // gemm blocks (64 rows)
    const int FLB = ((NN + NPW - 1) / NPW + 3) / 4;       // fused blocks
    const int GUB = ((NN + GNPW - 1) / GNPW + 3) / 4;     // gate blocks

    // encoder: X = relu(x@enc_w+b); Xbf = bf16(dis*X)
    gemm64b<IND, true, true><<<GB, 256, 0, stream>>>(x, enc_w, enc_b, dis, X, Xbf, NN);

    for (int l = 0; l < DEPTH; ++l) {
        fused_layer<<<FLB, 256, 0, stream>>>(Xbf, conv_w, conv_b, gg_w, gg_b,
                                             off_dst, sbd, dis, B, Cbf);
        gate_update4<<<GUB, 256, 0, stream>>>(Cbf, B, X, Xbf, off_src, dbs, cntf, dis);
    }

    // decoder
    gemm64b<NH, true, false><<<GB, 256, 0, stream>>>(X, dec_w, dec_b, nullptr, out, nullptr, NN);
}

// Round 5
// 853.225 us; speedup vs baseline: 1.4825x; 1.0961x over previous
//
#include <hip/hip_runtime.h>
#include <math.h>

#define NN 50000
#define NE 800000
#define IND 256
#define NH 64
#define DEPTH 4
#define NPW 4    // nodes per wave, fused_layer
#define GNPW 2   // nodes per wave, gate_update
#define PART_DIV 6250   // ceil(NN/8): node partition for XCD-local scatter

// ---------------- bf16 helpers ----------------

__device__ __forceinline__ float bf2f(unsigned short u) {
    return __uint_as_float(((unsigned int)u) << 16);
}
__device__ __forceinline__ unsigned short f2bf(float f) {
    unsigned int x = __float_as_uint(f);
    unsigned int r = (x + 0x7fffu + ((x >> 16) & 1u)) >> 16;
    return (unsigned short)r;
}
__device__ __forceinline__ float4 us4_to_f4(ushort4 u) {
    return make_float4(bf2f(u.x), bf2f(u.y), bf2f(u.z), bf2f(u.w));
}
__device__ __forceinline__ ushort4 f4_to_us4(float4 f) {
    ushort4 u;
    u.x = f2bf(f.x); u.y = f2bf(f.y); u.z = f2bf(f.z); u.w = f2bf(f.w);
    return u;
}

// ---------------- CSR build ----------------

__global__ void count_deg(const int* __restrict__ src, const int* __restrict__ dst,
                          int* __restrict__ degin, int* __restrict__ degout) {
    int e = blockIdx.x * blockDim.x + threadIdx.x;
    if (e < NE) {
        atomicAdd(&degout[src[e]], 1);
        atomicAdd(&degin[dst[e]], 1);
    }
}

// block b scans input b: exclusive scan of n ints, out has n+1 entries
__global__ void scan2(const int* __restrict__ in0, int* __restrict__ out0,
                      const int* __restrict__ in1, int* __restrict__ out1, int n) {
    __shared__ int sums[1024];
    const int* in = blockIdx.x ? in1 : in0;
    int* out = blockIdx.x ? out1 : out0;
    int t = threadIdx.x;
    int chunk = (n + 1023) / 1024;
    int lo = t * chunk;
    int hi = lo + chunk; if (hi > n) hi = n;
    int s = 0;
    for (int i = lo; i < hi; ++i) s += in[i];
    sums[t] = s;
    __syncthreads();
    for (int off = 1; off < 1024; off <<= 1) {
        int v = (t >= off) ? sums[t - off] : 0;
        __syncthreads();
        sums[t] += v;
        __syncthreads();
    }
    int run = (t == 0) ? 0 : sums[t - 1];
    for (int i = lo; i < hi; ++i) { out[i] = run; run += in[i]; }
    if (t == 0) out[n] = sums[1023];
}

__global__ void init_node(const int* __restrict__ degin, const int* __restrict__ degout,
                          const int* __restrict__ off_dst, const int* __restrict__ off_src,
                          int* __restrict__ cur_dst, int* __restrict__ cur_src,
                          float* __restrict__ dis, float* __restrict__ cntf) {
    int i = blockIdx.x * blockDim.x + threadIdx.x;
    if (i < NN) {
        dis[i] = rsqrtf((float)(degin[i] + 1));   // +1 self loop; always >0
        int od = degout[i];
        cntf[i] = (float)(od > 0 ? od : 1);
        cur_dst[i] = off_dst[i];
        cur_src[i] = off_src[i];
    }
}

// XCD-partitioned scatter: p = blockIdx&7 maps round-robin to XCDs.
// Each block scans all edges; performs the dst-grouped scatter only when
// dst/PART_DIV == p and the src-grouped scatter only when src/PART_DIV == p.
// All stores to one CSR slice then come from one XCD -> lines dirtied once,
// coalesced in that XCD's L2 (kills the 105 MB write-allocate thrash).
// Correctness does NOT depend on the block->XCD mapping (atomics device-scope).
__global__ void fill_csr_part(const int* __restrict__ src, const int* __restrict__ dst,
                              int* __restrict__ cur_dst, int* __restrict__ cur_src,
                              int* __restrict__ srcs_by_dst, int* __restrict__ dsts_by_src,
                              int nGroups) {
    int p = blockIdx.x & 7;
    int g = blockIdx.x >> 3;
    for (int e = g * 256 + threadIdx.x; e < NE; e += nGroups * 256) {
        int s = src[e], d = dst[e];
        if (d / PART_DIV == p) {
            int pos = atomicAdd(&cur_dst[d], 1);
            srcs_by_dst[pos] = s;
        }
        if (s / PART_DIV == p) {
            int pos = atomicAdd(&cur_src[s], 1);
            dsts_by_src[pos] = d;
        }
    }
}

// ---------------- helpers ----------------

__device__ __forceinline__ float4 bfly_sum(float4 v) {
    v.x += __shfl_xor(v.x, 16); v.y += __shfl_xor(v.y, 16);
    v.z += __shfl_xor(v.z, 16); v.w += __shfl_xor(v.w, 16);
    v.x += __shfl_xor(v.x, 32); v.y += __shfl_xor(v.y, 32);
    v.z += __shfl_xor(v.z, 32); v.w += __shfl_xor(v.w, 32);
    return v;
}

// ---------------- GEMM: [n,K] @ [K,64], 64 rows per block ----------------
// WSC: also write xsc row = bf16(rowscale[row] * result)
template<int K, bool RELU, bool WSC>
__global__ __launch_bounds__(256) void gemm64b(const float* __restrict__ X,
                                               const float* __restrict__ W,
                                               const float* __restrict__ bias,
                                               const float* __restrict__ rowscale,
                                               float* __restrict__ out,
                                               unsigned short* __restrict__ xsc, int n) {
    __shared__ float Ws[64 * 64];
    __shared__ float Xs[64][68];
    int tid = threadIdx.x;
    int row0 = blockIdx.x * 64;
    int r16 = tid >> 4;      // 0..15
    int cg = tid & 15;       // 0..15
    float4 acc[4];
#pragma unroll
    for (int t = 0; t < 4; ++t) acc[t] = make_float4(0.f, 0.f, 0.f, 0.f);

    for (int kc = 0; kc < K; kc += 64) {
        const float4* W4 = (const float4*)(W + (size_t)kc * 64);
        float4* Ws4 = (float4*)Ws;
#pragma unroll
        for (int t = 0; t < 4; ++t) Ws4[tid + t * 256] = W4[tid + t * 256];
#pragma unroll
        for (int t = 0; t < 4; ++t) {
            int r = r16 + t * 16;
            int grow = row0 + r;
            float4 xv = make_float4(0.f, 0.f, 0.f, 0.f);
            if (grow < n) xv = *(const float4*)(X + (size_t)grow * K + kc + cg * 4);
            Xs[r][cg * 4 + 0] = xv.x; Xs[r][cg * 4 + 1] = xv.y;
            Xs[r][cg * 4 + 2] = xv.z; Xs[r][cg * 4 + 3] = xv.w;
        }
        __syncthreads();
#pragma unroll
        for (int k = 0; k < 64; ++k) {
            float4 w4 = ((const float4*)Ws)[k * 16 + cg];
#pragma unroll
            for (int t = 0; t < 4; ++t) {
                float xv = Xs[r16 + t * 16][k];
                acc[t].x += xv * w4.x; acc[t].y += xv * w4.y;
                acc[t].z += xv * w4.z; acc[t].w += xv * w4.w;
            }
        }
        __syncthreads();
    }

    float4 b4 = ((const float4*)bias)[cg];
#pragma unroll
    for (int t = 0; t < 4; ++t) {
        int row = row0 + r16 + t * 16;
        if (row < n) {
            float4 o;
            o.x = acc[t].x + b4.x; o.y = acc[t].y + b4.y;
            o.z = acc[t].z + b4.z; o.w = acc[t].w + b4.w;
            if (RELU) {
                o.x = fmaxf(o.x, 0.f); o.y = fmaxf(o.y, 0.f);
                o.z = fmaxf(o.z, 0.f); o.w = fmaxf(o.w, 0.f);
            }
            ((float4*)(out + (size_t)row * 64))[cg] = o;
            if (WSC) {
                float s = rowscale[row];
                float4 o2 = make_float4(o.x * s, o.y * s, o.z * s, o.w * s);
                ((ushort4*)(xsc + (size_t)row * 64))[cg] = f4_to_us4(o2);
            }
        }
    }
}

// ---------------- fused layer: Z-aggregation + dual GEMV ----------------
// Xb (bf16) holds dis_i * X[i].
// Z[i] = dis_i * (sum_{s in in(i)} Xb[s] + Xb[i])
// B[i] = relu(Z[i] @ Wb + bb)   (conv candidate X_, fp32)
// C[i] = relu(Z[i] @ Wc + bc)   (gate xg, bf16)
__global__ __launch_bounds__(256) void fused_layer(
    const unsigned short* __restrict__ Xbf,
    const float* __restrict__ Wb, const float* __restrict__ bb,
    const float* __restrict__ Wc, const float* __restrict__ bc,
    const int* __restrict__ off, const int* __restrict__ nbr,
    const float* __restrict__ dis,
    float* __restrict__ B, unsigned short* __restrict__ Cbf)
{
    __shared__ float Ws[2][64 * 64];
    int tid = threadIdx.x;
    {
        const float4* wb4 = (const float4*)Wb;
        const float4* wc4 = (const float4*)Wc;
        float4* s0 = (float4*)Ws[0];
        float4* s1 = (float4*)Ws[1];
#pragma unroll
        for (int t = 0; t < 4; ++t) {
            s0[tid + t * 256] = wb4[tid + t * 256];
            s1[tid + t * 256] = wc4[tid + t * 256];
        }
    }
    __syncthreads();

    int lane = tid & 63;
    int q = lane >> 4;       // quarter 0..3
    int c = lane & 15;       // float4 / ushort4 group 0..15
    float4 bbv = ((const float4*)bb)[c];
    float4 bcv = ((const float4*)bc)[c];

    const ushort4* Xb = (const ushort4*)Xbf;   // row pitch = 16 ushort4

    int wave = blockIdx.x * 4 + (tid >> 6);
    int node0 = wave * NPW;
    int nodeEnd = node0 + NPW; if (nodeEnd > NN) nodeEnd = NN;

    for (int node = node0; node < nodeEnd; ++node) {
        int lo = off[node], hi = off[node + 1];
        float4 self = us4_to_f4(Xb[(size_t)node * 16 + c]);
        float di = dis[node];

        float4 z = make_float4(0.f, 0.f, 0.f, 0.f);
        int j = lo + q;
        // unrolled x4: 4 independent row loads in flight per quarter (16/wave)
        for (; j + 12 < hi; j += 16) {
            int s0 = nbr[j], s1 = nbr[j + 4], s2 = nbr[j + 8], s3 = nbr[j + 12];
            ushort4 r0 = Xb[(size_t)s0 * 16 + c];
            ushort4 r1 = Xb[(size_t)s1 * 16 + c];
            ushort4 r2 = Xb[(size_t)s2 * 16 + c];
            ushort4 r3 = Xb[(size_t)s3 * 16 + c];
            z.x += (bf2f(r0.x) + bf2f(r1.x)) + (bf2f(r2.x) + bf2f(r3.x));
            z.y += (bf2f(r0.y) + bf2f(r1.y)) + (bf2f(r2.y) + bf2f(r3.y));
            z.z += (bf2f(r0.z) + bf2f(r1.z)) + (bf2f(r2.z) + bf2f(r3.z));
            z.w += (bf2f(r0.w) + bf2f(r1.w)) + (bf2f(r2.w) + bf2f(r3.w));
        }
        for (; j < hi; j += 4) {
            int s = nbr[j];
            float4 r = us4_to_f4(Xb[(size_t)s * 16 + c]);
            z.x += r.x; z.y += r.y; z.z += r.z; z.w += r.w;
        }
        z = bfly_sum(z);
        z.x = di * (z.x + self.x);
        z.y = di * (z.y + self.y);
        z.z = di * (z.z + self.z);
        z.w = di * (z.w + self.w);

        // dual GEMV: lane (q,c) covers k in [16q,16q+16), outputs 4c..4c+3
        float4 ab = make_float4(0.f, 0.f, 0.f, 0.f);
        float4 ac = make_float4(0.f, 0.f, 0.f, 0.f);
#pragma unroll
        for (int kk = 0; kk < 16; ++kk) {
            float zsrc = ((kk & 3) == 0) ? z.x : ((kk & 3) == 1) ? z.y
                       : ((kk & 3) == 2) ? z.z : z.w;
            float zk = __shfl(zsrc, q * 4 + (kk >> 2));
            int k = q * 16 + kk;
            float4 wb = *(const float4*)&Ws[0][k * 64 + c * 4];
            float4 wc = *(const float4*)&Ws[1][k * 64 + c * 4];
            ab.x += zk * wb.x; ab.y += zk * wb.y; ab.z += zk * wb.z; ab.w += zk * wb.w;
            ac.x += zk * wc.x; ac.y += zk * wc.y; ac.z += zk * wc.z; ac.w += zk * wc.w;
        }
        ab = bfly_sum(ab);
        ac = bfly_sum(ac);
        if (q == 0) {
            float4 o;
            o.x = fmaxf(ab.x + bbv.x, 0.f); o.y = fmaxf(ab.y + bbv.y, 0.f);
            o.z = fmaxf(ab.z + bbv.z, 0.f); o.w = fmaxf(ab.w + bbv.w, 0.f);
            *(float4*)(B + (size_t)node * 64 + c * 4) = o;
        } else if (q == 1) {
            float4 o;
            o.x = fmaxf(ac.x + bcv.x, 0.f); o.y = fmaxf(ac.y + bcv.y, 0.f);
            o.z = fmaxf(ac.z + bcv.z, 0.f); o.w = fmaxf(ac.w + bcv.w, 0.f);
            ((ushort4*)Cbf)[(size_t)node * 16 + c] = f4_to_us4(o);
        }
    }
}

// ---------------- gate + convex update ----------------
// tau = tanh( sum_{d in out(i)} (xg_i - xg_d)^2 / cnt_i )   per channel
// X = (1-tau)*X + tau*Xn ; Xbf(bf16) = dis*X for next layer's gather
__global__ __launch_bounds__(256) void gate_update4(
    const unsigned short* __restrict__ Cbf, const float* __restrict__ Xn,
    float* __restrict__ X, unsigned short* __restrict__ Xbf,
    const int* __restrict__ off, const int* __restrict__ nbr,
    const float* __restrict__ cntf, const float* __restrict__ dis)
{
    int tid = threadIdx.x;
    int lane = tid & 63;
    int q = lane >> 4;
    int c = lane & 15;
    const ushort4* Cb = (const ushort4*)Cbf;
    int wave = blockIdx.x * 4 + (tid >> 6);
    int node0 = wave * GNPW;
    int nodeEnd = node0 + GNPW; if (nodeEnd > NN) nodeEnd = NN;

    for (int node = node0; node < nodeEnd; ++node) {
        float4 xg = us4_to_f4(Cb[(size_t)node * 16 + c]);
        float4 xo = *(const float4*)(X + (size_t)node * 64 + c * 4);
        float4 xn = *(const float4*)(Xn + (size_t)node * 64 + c * 4);
        float inv = 1.f / cntf[node];
        float di = dis[node];

        float4 acc = make_float4(0.f, 0.f, 0.f, 0.f);
        int lo = off[node], hi = off[node + 1];
        int j = lo + q;
        for (; j + 12 < hi; j += 16) {
            int d0 = nbr[j], d1 = nbr[j + 4], d2 = nbr[j + 8], d3 = nbr[j + 12];
            float4 r0 = us4_to_f4(Cb[(size_t)d0 * 16 + c]);
            float4 r1 = us4_to_f4(Cb[(size_t)d1 * 16 + c]);
            float4 r2 = us4_to_f4(Cb[(size_t)d2 * 16 + c]);
            float4 r3 = us4_to_f4(Cb[(size_t)d3 * 16 + c]);
            float e;
            e = xg.x - r0.x; acc.x += e * e;  e = xg.y - r0.y; acc.y += e * e;
            e = xg.z - r0.z; acc.z += e * e;  e = xg.w - r0.w; acc.w += e * e;
            e = xg.x - r1.x; acc.x += e * e;  e = xg.y - r1.y; acc.y += e * e;
            e = xg.z - r1.z; acc.z += e * e;  e = xg.w - r1.w; acc.w += e * e;
            e = xg.x - r2.x; acc.x += e * e;  e = xg.y - r2.y; acc.y += e * e;
            e = xg.z - r2.z; acc.z += e * e;  e = xg.w - r2.w; acc.w += e * e;
            e = xg.x - r3.x; acc.x += e * e;  e = xg.y - r3.y; acc.y += e * e;
            e = xg.z - r3.z; acc.z += e * e;  e = xg.w - r3.w; acc.w += e * e;
        }
        for (; j < hi; j += 4) {
            int d = nbr[j];
            float4 xd = us4_to_f4(Cb[(size_t)d * 16 + c]);
            float e;
            e = xg.x - xd.x; acc.x += e * e;  e = xg.y - xd.y; acc.y += e * e;
            e = xg.z - xd.z; acc.z += e * e;  e = xg.w - xd.w; acc.w += e * e;
        }
        acc = bfly_sum(acc);
        if (q == 0) {
            float4 tau;
            tau.x = tanhf(acc.x * inv); tau.y = tanhf(acc.y * inv);
            tau.z = tanhf(acc.z * inv); tau.w = tanhf(acc.w * inv);
            float4 o;
            o.x = xo.x + tau.x * (xn.x - xo.x);
            o.y = xo.y + tau.y * (xn.y - xo.y);
            o.z = xo.z + tau.z * (xn.z - xo.z);
            o.w = xo.w + tau.w * (xn.w - xo.w);
            *(float4*)(X + (size_t)node * 64 + c * 4) = o;
            float4 o2 = make_float4(o.x * di, o.y * di, o.z * di, o.w * di);
            ((ushort4*)Xbf)[(size_t)node * 16 + c] = f4_to_us4(o2);
        }
    }
}

// ---------------- launch ----------------

extern "C" void kernel_launch(void* const* d_in, const int* in_sizes, int n_in,
                              void* d_out, int out_size, void* d_ws, size_t ws_size,
                              hipStream_t stream) {
    const float* x      = (const float*)d_in[0];
    const int*   ei     = (const int*)d_in[1];
    const float* enc_w  = (const float*)d_in[2];
    const float* enc_b  = (const float*)d_in[3];
    const float* conv_w = (const float*)d_in[4];
    const float* conv_b = (const float*)d_in[5];
    const float* gg_w   = (const float*)d_in[6];
    const float* gg_b   = (const float*)d_in[7];
    const float* dec_w  = (const float*)d_in[8];
    const float* dec_b  = (const float*)d_in[9];
    float* out = (float*)d_out;

    const int* src = ei;
    const int* dst = ei + NE;

    char* p = (char*)d_ws;
    auto alloc = [&](size_t bytes) -> void* {
        void* r = (void*)p;
        p += (bytes + 255) & ~(size_t)255;
        return r;
    };
    float* X   = (float*)alloc((size_t)NN * 64 * 4);
    float* B   = (float*)alloc((size_t)NN * 64 * 4);           // X_ candidate (fp32)
    unsigned short* Xbf = (unsigned short*)alloc((size_t)NN * 64 * 2);  // dis*X, bf16
    unsigned short* Cbf = (unsigned short*)alloc((size_t)NN * 64 * 2);  // xg, bf16
    float* dis  = (float*)alloc((size_t)NN * 4);
    float* cntf = (float*)alloc((size_t)NN * 4);
    int* degin   = (int*)alloc((size_t)NN * 4);
    int* degout  = (int*)alloc((size_t)NN * 4);
    int* off_dst = (int*)alloc((size_t)(NN + 1) * 4);
    int* off_src = (int*)alloc((size_t)(NN + 1) * 4);
    int* cur_dst = (int*)alloc((size_t)NN * 4);
    int* cur_src = (int*)alloc((size_t)NN * 4);
    int* sbd     = (int*)alloc((size_t)NE * 4);   // srcs grouped by dst
    int* dbs     = (int*)alloc((size_t)NE * 4);   // dsts grouped by src

    hipMemsetAsync(degin, 0, (size_t)NN * 4, stream);
    hipMemsetAsync(degout, 0, (size_t)NN * 4, stream);

    const int EB = (NE + 255) / 256;
    const int NB = (NN + 255) / 256;
    count_deg<<<EB, 256, 0, stream>>>(src, dst, degin, degout);
    scan2<<<2, 1024, 0, stream>>>(degin, off_dst, degout, off_src, NN);
    init_node<<<NB, 256, 0, stream>>>(degin, degout, off_dst, off_src,
                                      cur_dst, cur_src, dis, cntf);
    const int NGROUPS = 104;   // 8*104 = 832 blocks (~3.25/CU)
    fill_csr_part<<<8 * NGROUPS, 256, 0, stream>>>(src, dst, cur_dst, cur_src,
                                                   sbd, dbs, NGROUPS);

    const int GB  = (NN + 63) / 64;                       // gemm blocks (64 rows)
    const int FLB = ((NN + NPW - 1) / NPW + 3) / 4;       // fused blocks
    const int GUB = ((NN + GNPW - 1) / GNPW + 3) / 4;     // gate blocks

    // encoder: X = relu(x@enc_w+b); Xbf = bf16(dis*X)
    gemm64b<IND, true, true><<<GB, 256, 0, stream>>>(x, enc_w, enc_b, dis, X, Xbf, NN);

    for (int l = 0; l < DEPTH; ++l) {
        fused_layer<<<FLB, 256, 0, stream>>>(Xbf, conv_w, conv_b, gg_w, gg_b,
                                             off_dst, sbd, dis, B, Cbf);
        gate_update4<<<GUB, 256, 0, stream>>>(Cbf, B, X, Xbf, off_src, dbs, cntf, dis);
    }

    // decoder
    gemm64b<NH, true, false><<<GB, 256, 0, stream>>>(X, dec_w, dec_b, nullptr, out, nullptr, NN);
}